// Round 2
// baseline (106.783 us; speedup 1.0000x reference)
//
#include <hip/hip_runtime.h>

using uint = unsigned int;
typedef unsigned short ushort_t;
typedef float f32x4 __attribute__((ext_vector_type(4)));

#define B_ 4
#define C_ 256
#define T_ 4096
#define U_ 64

static __device__ __forceinline__ float bflo(uint w) { return __uint_as_float(w << 16); }
static __device__ __forceinline__ float bfhi(uint w) { return __uint_as_float(w & 0xffff0000u); }
static __device__ __forceinline__ uint f2bf(float f) {
    uint x = __float_as_uint(f);
    return (x + 0x7fffu + ((x >> 16) & 1u)) >> 16;
}

// ---------------------------------------------------------------------------
// Kernel 1: projections.  blockIdx.y==0 -> Q from y1;  ==1 -> K,V from y2.
// Q/K/V stored bf16 [B][T][64] in workspace (as packed uint pairs).
// ---------------------------------------------------------------------------
__global__ __launch_bounds__(512) void proj_kernel(
    const float* __restrict__ y1, const float* __restrict__ y2,
    const float* __restrict__ Wq, const float* __restrict__ Wk,
    const float* __restrict__ Wv,
    uint* __restrict__ Qb, uint* __restrict__ Kb, uint* __restrict__ Vb)
{
    __shared__ float ylds[C_][64];      // 64 KB
    __shared__ uint  wa[C_][32];        // 32 KB (bf16x2)
    __shared__ uint  wb[C_][32];        // 32 KB (bf16x2)

    const int p   = blockIdx.y;
    const int b   = blockIdx.x >> 6;
    const int t0  = (blockIdx.x & 63) << 6;
    const int tid = threadIdx.x;

    const float* ysrc = (p == 0 ? y1 : y2) + (size_t)b * C_ * T_ + t0;

    // stage y tile [256 c][64 t] (fp32)
    {
        const int tq4 = tid & 15, cb = tid >> 4;   // 32 c per pass
#pragma unroll
        for (int k = 0; k < 8; ++k) {
            int c = cb + 32 * k;
            float4 v = *(const float4*)(ysrc + (size_t)c * T_ + 4 * tq4);
            *(float4*)&ylds[c][4 * tq4] = v;
        }
    }
    // stage W (bf16 packed)
    {
        const float* W0 = (p == 0) ? Wq : Wk;
#pragma unroll
        for (int k = 0; k < 16; ++k) {
            int idx = tid + 512 * k;                 // 8192 float2 pairs
            float2 w = *(const float2*)(W0 + 2 * idx);
            ((uint*)wa)[idx] = f2bf(w.x) | (f2bf(w.y) << 16);
        }
        if (p == 1) {
#pragma unroll
            for (int k = 0; k < 16; ++k) {
                int idx = tid + 512 * k;
                float2 w = *(const float2*)(Wv + 2 * idx);
                ((uint*)wb)[idx] = f2bf(w.x) | (f2bf(w.y) << 16);
            }
        }
    }
    __syncthreads();

    const int uq = tid & 31;       // u pair index (u = 2*uq, 2*uq+1)
    const int tq = tid >> 5;       // t group (t = 4*tq + i)

    if (p == 0) {
        float a0[4] = {0,0,0,0}, a1[4] = {0,0,0,0};
#pragma unroll 4
        for (int c = 0; c < C_; ++c) {
            float4 yv = *(float4*)&ylds[c][4 * tq];
            uint w = wa[c][uq];
            float wl = bflo(w), wh = bfhi(w);
            a0[0] = fmaf(yv.x, wl, a0[0]);  a1[0] = fmaf(yv.x, wh, a1[0]);
            a0[1] = fmaf(yv.y, wl, a0[1]);  a1[1] = fmaf(yv.y, wh, a1[1]);
            a0[2] = fmaf(yv.z, wl, a0[2]);  a1[2] = fmaf(yv.z, wh, a1[2]);
            a0[3] = fmaf(yv.w, wl, a0[3]);  a1[3] = fmaf(yv.w, wh, a1[3]);
        }
#pragma unroll
        for (int i2 = 0; i2 < 4; ++i2) {
            int t = t0 + 4 * tq + i2;
            Qb[((size_t)b * T_ + t) * 32 + uq] = f2bf(a0[i2]) | (f2bf(a1[i2]) << 16);
        }
    } else {
        float k0[4] = {0,0,0,0}, k1[4] = {0,0,0,0};
        float v0[4] = {0,0,0,0}, v1[4] = {0,0,0,0};
#pragma unroll 4
        for (int c = 0; c < C_; ++c) {
            float4 yv = *(float4*)&ylds[c][4 * tq];
            uint w  = wa[c][uq];
            uint w2 = wb[c][uq];
            float kl = bflo(w),  kh = bfhi(w);
            float vl = bflo(w2), vh = bfhi(w2);
            k0[0] = fmaf(yv.x, kl, k0[0]);  k1[0] = fmaf(yv.x, kh, k1[0]);
            k0[1] = fmaf(yv.y, kl, k0[1]);  k1[1] = fmaf(yv.y, kh, k1[1]);
            k0[2] = fmaf(yv.z, kl, k0[2]);  k1[2] = fmaf(yv.z, kh, k1[2]);
            k0[3] = fmaf(yv.w, kl, k0[3]);  k1[3] = fmaf(yv.w, kh, k1[3]);
            v0[0] = fmaf(yv.x, vl, v0[0]);  v1[0] = fmaf(yv.x, vh, v1[0]);
            v0[1] = fmaf(yv.y, vl, v0[1]);  v1[1] = fmaf(yv.y, vh, v1[1]);
            v0[2] = fmaf(yv.z, vl, v0[2]);  v1[2] = fmaf(yv.z, vh, v1[2]);
            v0[3] = fmaf(yv.w, vl, v0[3]);  v1[3] = fmaf(yv.w, vh, v1[3]);
        }
#pragma unroll
        for (int i2 = 0; i2 < 4; ++i2) {
            int t = t0 + 4 * tq + i2;
            Kb[((size_t)b * T_ + t) * 32 + uq] = f2bf(k0[i2]) | (f2bf(k1[i2]) << 16);
            Vb[((size_t)b * T_ + t) * 32 + uq] = f2bf(v0[i2]) | (f2bf(v1[i2]) << 16);
        }
    }
}

// ---------------------------------------------------------------------------
// Kernel 2: banded attention. 1024 blocks (b, 16-row tile), 256 threads.
// Each wave owns 4 rows. Writes full a rows (zeros + band) + out[b][u][i].
// ---------------------------------------------------------------------------
__global__ __launch_bounds__(256, 2) void attn_kernel(
    const uint* __restrict__ Qb, const uint* __restrict__ Kb,
    const uint* __restrict__ Vb, float* __restrict__ gout)
{
    __shared__ alignas(16) uint kw[271 * 32];       // 34,688 B  (bf16x2, XOR-swizzled)
    __shared__ alignas(16) uint vw[271 * 32];       // 34,688 B
    __shared__ float   qlds[16][64];                // 4 KB fp32
    __shared__ ushort_t alds[4][256];               // 2 KB (a as bf16, per wave)
    __shared__ float   olds[64][17];                // 4.25 KB (out accumulator)

    const int bid = blockIdx.x;
    const int b   = bid >> 8;
    const int i0  = (bid & 255) << 4;
    const int tid = threadIdx.x;

    const int jb    = max(0, i0 - 127);
    const int jend  = min(T_, i0 + 16 + 128);
    const int width = jend - jb;                    // 144..271

    // ---- stage K/V window (swizzled) ----
    {
        const uint4* ks = (const uint4*)(Kb + ((size_t)b * T_ + jb) * 32);
        const uint4* vs = (const uint4*)(Vb + ((size_t)b * T_ + jb) * 32);
        int n4 = width * 8;
        for (int idx = tid; idx < n4; idx += 256) {
            int row  = idx >> 3;
            int q4   = (idx & 7) << 2;
            int phys = q4 ^ ((row & 7) << 2);
            *(uint4*)&kw[row * 32 + phys] = ks[idx];
            *(uint4*)&vw[row * 32 + phys] = vs[idx];
        }
    }
    // ---- stage Q tile (bf16 -> fp32) ----
    {
        const uint* qs = Qb + ((size_t)b * T_ + i0) * 32;
        for (int idx = tid; idx < 512; idx += 256) {
            uint w = qs[idx];
            float2 f; f.x = bflo(w); f.y = bfhi(w);
            ((float2*)qlds)[idx] = f;
        }
    }
    __syncthreads();

    const int wv = tid >> 6;
    const int l  = tid & 63;
    float* aout = gout + (size_t)B_ * U_ * T_;      // a region

    for (int rr = 0; rr < 4; ++rr) {
        const int r = 4 * wv + rr;
        const int i = i0 + r;
        const int jlo = max(0, i - 127);
        const int jhi = min(T_ - 1, i + 128);
        float* rowp = aout + ((size_t)(b * T_ + i)) * T_;
        f32x4* row4 = (f32x4*)rowp;

        // 1) zero the full row (in flight while we compute S)
        f32x4 z = (f32x4)(0.f);
#pragma unroll
        for (int k = 0; k < 16; ++k)
            __builtin_nontemporal_store(z, row4 + l + 64 * k);

        // 2) S = q . K  for 4 j's per lane
        const int rowoff = jlo - jb;
        int jlbase[4], sel[4];
        bool valid[4];
#pragma unroll
        for (int p = 0; p < 4; ++p) {
            int joff = l + 64 * p;
            valid[p] = (jlo + joff) <= jhi;
            int t = rowoff + joff;
            if (t > width - 1) t = width - 1;
            jlbase[p] = t * 32;
            sel[p]    = (t & 7) << 2;
        }
        float S[4] = {0.f, 0.f, 0.f, 0.f};
#pragma unroll
        for (int m = 0; m < 8; ++m) {
            float4 q0 = *(float4*)&qlds[r][8 * m];
            float4 q1 = *(float4*)&qlds[r][8 * m + 4];
#pragma unroll
            for (int p = 0; p < 4; ++p) {
                uint4 kk = *(uint4*)&kw[jlbase[p] + ((4 * m) ^ sel[p])];
                float s = S[p];
                s = fmaf(q0.x, bflo(kk.x), s);  s = fmaf(q0.y, bfhi(kk.x), s);
                s = fmaf(q0.z, bflo(kk.y), s);  s = fmaf(q0.w, bfhi(kk.y), s);
                s = fmaf(q1.x, bflo(kk.z), s);  s = fmaf(q1.y, bfhi(kk.z), s);
                s = fmaf(q1.z, bflo(kk.w), s);  s = fmaf(q1.w, bfhi(kk.w), s);
                S[p] = s;
            }
        }

        // 3) softmax along the band (|e| small -> no max subtraction needed)
        float e[4], esum = 0.f;
#pragma unroll
        for (int p = 0; p < 4; ++p) {
            e[p] = valid[p] ? __expf(S[p] * 0.125f) : 0.f;
            esum += e[p];
        }
#pragma unroll
        for (int d = 1; d < 64; d <<= 1)
            esum += __shfl_xor(esum, d, 64);
        float rinv = __builtin_amdgcn_rcpf(esum);
        float av[4];
#pragma unroll
        for (int p = 0; p < 4; ++p) av[p] = e[p] * rinv;

        // 4) band values overwrite zeros (same wave; wait for zero stores)
        asm volatile("s_waitcnt vmcnt(0)" ::: "memory");
#pragma unroll
        for (int p = 0; p < 4; ++p) {
            if (valid[p])
                __builtin_nontemporal_store(av[p], rowp + jlo + l + 64 * p);
            alds[wv][l + 64 * p] = (ushort_t)f2bf(av[p]);   // 0 when invalid
        }
        asm volatile("s_waitcnt lgkmcnt(0)" ::: "memory");

        // 5) PV: lanes split 4 j-groups x 16 u-quads
        {
            const int jq = l >> 4, uq = l & 15;
            float o0 = 0.f, o1 = 0.f, o2 = 0.f, o3 = 0.f;
#pragma unroll 8
            for (int jj = 0; jj < 64; ++jj) {
                int joff = 4 * jj + jq;
                float aw = __uint_as_float(((uint)alds[wv][joff]) << 16);
                int t = rowoff + joff;
                if (t > width - 1) t = width - 1;
                uint2 vv = *(uint2*)&vw[t * 32 + ((2 * uq) ^ ((t & 7) << 2))];
                o0 = fmaf(aw, bflo(vv.x), o0);
                o1 = fmaf(aw, bfhi(vv.x), o1);
                o2 = fmaf(aw, bflo(vv.y), o2);
                o3 = fmaf(aw, bfhi(vv.y), o3);
            }
            o0 += __shfl_xor(o0, 16, 64);  o0 += __shfl_xor(o0, 32, 64);
            o1 += __shfl_xor(o1, 16, 64);  o1 += __shfl_xor(o1, 32, 64);
            o2 += __shfl_xor(o2, 16, 64);  o2 += __shfl_xor(o2, 32, 64);
            o3 += __shfl_xor(o3, 16, 64);  o3 += __shfl_xor(o3, 32, 64);
            if (l < 16) {
                olds[4 * uq + 0][r] = o0;
                olds[4 * uq + 1][r] = o1;
                olds[4 * uq + 2][r] = o2;
                olds[4 * uq + 3][r] = o3;
            }
        }
    }
    __syncthreads();

    // 6) coalesced out[b][u][i0:i0+16] write
    {
        const int u = tid >> 2, e4 = tid & 3;
        f32x4 o;
        o.x = olds[u][4 * e4 + 0];
        o.y = olds[u][4 * e4 + 1];
        o.z = olds[u][4 * e4 + 2];
        o.w = olds[u][4 * e4 + 3];
        __builtin_nontemporal_store(o, (f32x4*)(gout + ((size_t)b * U_ + u) * T_ + i0 + 4 * e4));
    }
}

// ---------------------------------------------------------------------------
extern "C" void kernel_launch(void* const* d_in, const int* in_sizes, int n_in,
                              void* d_out, int out_size, void* d_ws, size_t ws_size,
                              hipStream_t stream)
{
    const float* y1 = (const float*)d_in[0];
    const float* y2 = (const float*)d_in[1];
    const float* Wq = (const float*)d_in[2];
    const float* Wk = (const float*)d_in[3];
    const float* Wv = (const float*)d_in[4];
    // d_in[5] = attention_width (== 256, compiled in)

    // workspace: Q, K, V as bf16 [B][T][64] -> 2 MB each (dword-packed)
    uint* Qb = (uint*)d_ws;
    uint* Kb = Qb + (size_t)B_ * T_ * 32;
    uint* Vb = Kb + (size_t)B_ * T_ * 32;

    float* gout = (float*)d_out;

    dim3 g1(B_ * (T_ / 64), 2);
    proj_kernel<<<g1, 512, 0, stream>>>(y1, y2, Wq, Wk, Wv, Qb, Kb, Vb);

    attn_kernel<<<dim3(B_ * (T_ / 16)), 256, 0, stream>>>(Qb, Kb, Vb, gout);
}

// Round 3
// 84.613 us; speedup vs baseline: 1.2620x; 1.2620x over previous
//
#include <hip/hip_runtime.h>

using uint = unsigned int;
typedef unsigned short ushort_t;
typedef float f32x4 __attribute__((ext_vector_type(4)));
typedef short short8 __attribute__((ext_vector_type(8)));

#define B_ 4
#define C_ 256
#define T_ 4096
#define U_ 64

static __device__ __forceinline__ float bflo(uint w) { return __uint_as_float(w << 16); }
static __device__ __forceinline__ float bfhi(uint w) { return __uint_as_float(w & 0xffff0000u); }
static __device__ __forceinline__ uint f2bf(float f) {
    uint x = __float_as_uint(f);
    return (x + 0x7fffu + ((x >> 16) & 1u)) >> 16;
}

// ---------------------------------------------------------------------------
// Kernel 1: MFMA projections. blockIdx.y==0 -> Q from y1; ==1 -> K,V from y2.
// GEMM: out[t,u] = sum_c y[c,t] * W[c,u].  A[m=t][k=c] read from global
// (lane pattern hits four full 64B lines per load inst), B = W^T staged in LDS.
// Q/K/V stored bf16 [B][T][64] (ushort) in workspace.
// ---------------------------------------------------------------------------
__global__ __launch_bounds__(256) void proj_kernel(
    const float* __restrict__ y1, const float* __restrict__ y2,
    const float* __restrict__ Wq, const float* __restrict__ Wk,
    const float* __restrict__ Wv,
    ushort_t* __restrict__ Qb, ushort_t* __restrict__ Kb, ushort_t* __restrict__ Vb)
{
    __shared__ alignas(16) ushort_t wt[2][64][264];   // W^T bf16, padded rows

    const int p   = blockIdx.y;
    const int b   = blockIdx.x >> 6;
    const int t0  = (blockIdx.x & 63) << 6;
    const int tid = threadIdx.x;

    // ---- stage W^T (bf16) ----
    {
        const float* W0 = (p == 0) ? Wq : Wk;
#pragma unroll
        for (int k = 0; k < 64; ++k) {
            int idx = tid + 256 * k;          // idx = c*64 + u
            int c = idx >> 6, u = idx & 63;
            wt[0][u][c] = (ushort_t)f2bf(W0[idx]);
        }
        if (p == 1) {
#pragma unroll
            for (int k = 0; k < 64; ++k) {
                int idx = tid + 256 * k;
                int c = idx >> 6, u = idx & 63;
                wt[1][u][c] = (ushort_t)f2bf(Wv[idx]);
            }
        }
    }
    __syncthreads();

    const int wid = tid >> 6, l = tid & 63;
    const int lm = l & 15, lg = l >> 4;

    const float* ysrc = ((p == 0) ? y1 : y2) + (size_t)b * (C_ * T_);
    const float* yp   = ysrc + (size_t)(8 * lg) * T_ + (t0 + 16 * wid + lm);

    // ---- A fragments: lane (lm,lg) holds A[t0+16w+lm][8lg + j + 32ks] ----
    float avf[8][8];
#pragma unroll
    for (int ks = 0; ks < 8; ++ks)
#pragma unroll
        for (int j = 0; j < 8; ++j)
            avf[ks][j] = yp[(size_t)(32 * ks + j) * T_];

    short8 afr[8];
#pragma unroll
    for (int ks = 0; ks < 8; ++ks)
#pragma unroll
        for (int j = 0; j < 8; ++j)
            afr[ks][j] = (short)f2bf(avf[ks][j]);

    f32x4 acc0[4] = {};
    f32x4 acc1[4] = {};
#pragma unroll
    for (int ks = 0; ks < 8; ++ks) {
#pragma unroll
        for (int n = 0; n < 4; ++n) {
            short8 bq = *(const short8*)&wt[0][16 * n + lm][32 * ks + 8 * lg];
            acc0[n] = __builtin_amdgcn_mfma_f32_16x16x32_bf16(afr[ks], bq, acc0[n], 0, 0, 0);
            if (p == 1) {
                short8 bv = *(const short8*)&wt[1][16 * n + lm][32 * ks + 8 * lg];
                acc1[n] = __builtin_amdgcn_mfma_f32_16x16x32_bf16(afr[ks], bv, acc1[n], 0, 0, 0);
            }
        }
    }

    // ---- epilogue: C/D layout col=lane&15 (u), row=(lane>>4)*4+reg (t) ----
    ushort_t* O0 = (p == 0) ? Qb : Kb;
#pragma unroll
    for (int n = 0; n < 4; ++n)
#pragma unroll
        for (int r = 0; r < 4; ++r) {
            int t = t0 + 16 * wid + 4 * lg + r;
            int u = 16 * n + lm;
            size_t off = ((size_t)b * T_ + t) * 64 + u;
            O0[off] = (ushort_t)f2bf(acc0[n][r]);
            if (p == 1) Vb[off] = (ushort_t)f2bf(acc1[n][r]);
        }
}

// ---------------------------------------------------------------------------
// Kernel 2: banded attention. 1024 blocks (b, 16-row tile), 256 threads.
// Each wave owns 4 rows. Single-pass row write: zeros-left | band | zeros-right.
// ---------------------------------------------------------------------------
__global__ __launch_bounds__(256, 2) void attn_kernel(
    const uint* __restrict__ Qb, const uint* __restrict__ Kb,
    const uint* __restrict__ Vb, float* __restrict__ gout)
{
    __shared__ alignas(16) uint kw[271 * 32];       // bf16x2, XOR-swizzled
    __shared__ alignas(16) uint vw[271 * 32];
    __shared__ float   qlds[16][64];
    __shared__ ushort_t alds[4][256];
    __shared__ float   olds[64][17];

    const int bid = blockIdx.x;
    const int b   = bid >> 8;
    const int i0  = (bid & 255) << 4;
    const int tid = threadIdx.x;

    const int jb    = max(0, i0 - 127);
    const int jend  = min(T_, i0 + 16 + 128);
    const int width = jend - jb;                    // 144..271

    // ---- stage K/V window (swizzled) ----
    {
        const uint4* ks = (const uint4*)(Kb + ((size_t)b * T_ + jb) * 32);
        const uint4* vs = (const uint4*)(Vb + ((size_t)b * T_ + jb) * 32);
        int n4 = width * 8;
        for (int idx = tid; idx < n4; idx += 256) {
            int row  = idx >> 3;
            int q4   = (idx & 7) << 2;
            int phys = q4 ^ ((row & 7) << 2);
            *(uint4*)&kw[row * 32 + phys] = ks[idx];
            *(uint4*)&vw[row * 32 + phys] = vs[idx];
        }
    }
    // ---- stage Q tile (bf16 -> fp32) ----
    {
        const uint* qs = Qb + ((size_t)b * T_ + i0) * 32;
        for (int idx = tid; idx < 512; idx += 256) {
            uint w = qs[idx];
            float2 f; f.x = bflo(w); f.y = bfhi(w);
            ((float2*)qlds)[idx] = f;
        }
    }
    __syncthreads();

    const int wv = tid >> 6;
    const int l  = tid & 63;
    float* aout = gout + (size_t)B_ * U_ * T_;      // a region

    for (int rr = 0; rr < 4; ++rr) {
        const int r = 4 * wv + rr;
        const int i = i0 + r;
        const int jlo = max(0, i - 127);
        const int jhi = min(T_ - 1, i + 128);
        float* rowp = aout + ((size_t)(b * T_ + i)) * T_;
        f32x4* row4 = (f32x4*)rowp;

        // 1) S = q . K  for 4 j's per lane
        const int rowoff = jlo - jb;
        int jlbase[4], sel[4];
        bool valid[4];
#pragma unroll
        for (int p = 0; p < 4; ++p) {
            int joff = l + 64 * p;
            valid[p] = (jlo + joff) <= jhi;
            int t = rowoff + joff;
            if (t > width - 1) t = width - 1;
            jlbase[p] = t * 32;
            sel[p]    = (t & 7) << 2;
        }
        float S[4] = {0.f, 0.f, 0.f, 0.f};
#pragma unroll
        for (int m = 0; m < 8; ++m) {
            float4 q0 = *(float4*)&qlds[r][8 * m];
            float4 q1 = *(float4*)&qlds[r][8 * m + 4];
#pragma unroll
            for (int p = 0; p < 4; ++p) {
                uint4 kk = *(uint4*)&kw[jlbase[p] + ((4 * m) ^ sel[p])];
                float s = S[p];
                s = fmaf(q0.x, bflo(kk.x), s);  s = fmaf(q0.y, bfhi(kk.x), s);
                s = fmaf(q0.z, bflo(kk.y), s);  s = fmaf(q0.w, bfhi(kk.y), s);
                s = fmaf(q1.x, bflo(kk.z), s);  s = fmaf(q1.y, bfhi(kk.z), s);
                s = fmaf(q1.z, bflo(kk.w), s);  s = fmaf(q1.w, bfhi(kk.w), s);
                S[p] = s;
            }
        }

        // 2) softmax along the band (scores are small -> no max subtraction)
        float e[4], esum = 0.f;
#pragma unroll
        for (int p = 0; p < 4; ++p) {
            e[p] = valid[p] ? __expf(S[p] * 0.125f) : 0.f;
            esum += e[p];
        }
#pragma unroll
        for (int d = 1; d < 64; d <<= 1)
            esum += __shfl_xor(esum, d, 64);
        float rinv = __builtin_amdgcn_rcpf(esum);
        float av[4];
#pragma unroll
        for (int p = 0; p < 4; ++p) av[p] = e[p] * rinv;

        // 3) single-pass row write: band values + zero segments (disjoint)
#pragma unroll
        for (int p = 0; p < 4; ++p) {
            if (valid[p])
                __builtin_nontemporal_store(av[p], rowp + jlo + l + 64 * p);
            alds[wv][l + 64 * p] = (ushort_t)f2bf(av[p]);   // 0 when invalid
        }
        {
            f32x4 z = (f32x4)(0.f);
            // zeros left of band: [0, jlo)
            int nleft4 = jlo >> 2;
            for (int k = l; k < nleft4; k += 64)
                __builtin_nontemporal_store(z, row4 + k);
            int rem = jlo & 3;
            if (l < rem)
                __builtin_nontemporal_store(0.f, rowp + (jlo & ~3) + l);
            // zeros right of band: (jhi, T)
            int js = jhi + 1;
            int ah = (4 - (js & 3)) & 3;
            if (l < ah)
                __builtin_nontemporal_store(0.f, rowp + js + l);
            int js4 = (js + ah) >> 2;
            for (int k = js4 + l; k < T_ / 4; k += 64)
                __builtin_nontemporal_store(z, row4 + k);
        }
        asm volatile("s_waitcnt lgkmcnt(0)" ::: "memory");

        // 4) PV: lanes split 4 j-groups x 16 u-quads
        {
            const int jq = l >> 4, uq = l & 15;
            float o0 = 0.f, o1 = 0.f, o2 = 0.f, o3 = 0.f;
#pragma unroll 8
            for (int jj = 0; jj < 64; ++jj) {
                int joff = 4 * jj + jq;
                float aw = __uint_as_float(((uint)alds[wv][joff]) << 16);
                int t = rowoff + joff;
                if (t > width - 1) t = width - 1;
                uint2 vv = *(uint2*)&vw[t * 32 + ((2 * uq) ^ ((t & 7) << 2))];
                o0 = fmaf(aw, bflo(vv.x), o0);
                o1 = fmaf(aw, bfhi(vv.x), o1);
                o2 = fmaf(aw, bflo(vv.y), o2);
                o3 = fmaf(aw, bfhi(vv.y), o3);
            }
            o0 += __shfl_xor(o0, 16, 64);  o0 += __shfl_xor(o0, 32, 64);
            o1 += __shfl_xor(o1, 16, 64);  o1 += __shfl_xor(o1, 32, 64);
            o2 += __shfl_xor(o2, 16, 64);  o2 += __shfl_xor(o2, 32, 64);
            o3 += __shfl_xor(o3, 16, 64);  o3 += __shfl_xor(o3, 32, 64);
            if (l < 16) {
                olds[4 * uq + 0][r] = o0;
                olds[4 * uq + 1][r] = o1;
                olds[4 * uq + 2][r] = o2;
                olds[4 * uq + 3][r] = o3;
            }
        }
    }
    __syncthreads();

    // 5) coalesced out[b][u][i0:i0+16] write
    {
        const int u = tid >> 2, e4 = tid & 3;
        f32x4 o;
        o.x = olds[u][4 * e4 + 0];
        o.y = olds[u][4 * e4 + 1];
        o.z = olds[u][4 * e4 + 2];
        o.w = olds[u][4 * e4 + 3];
        __builtin_nontemporal_store(o, (f32x4*)(gout + ((size_t)b * U_ + u) * T_ + i0 + 4 * e4));
    }
}

// ---------------------------------------------------------------------------
extern "C" void kernel_launch(void* const* d_in, const int* in_sizes, int n_in,
                              void* d_out, int out_size, void* d_ws, size_t ws_size,
                              hipStream_t stream)
{
    const float* y1 = (const float*)d_in[0];
    const float* y2 = (const float*)d_in[1];
    const float* Wq = (const float*)d_in[2];
    const float* Wk = (const float*)d_in[3];
    const float* Wv = (const float*)d_in[4];
    // d_in[5] = attention_width (== 256, compiled in)

    // workspace: Q, K, V as bf16 [B][T][64] -> 2 MB each
    ushort_t* Qb = (ushort_t*)d_ws;
    ushort_t* Kb = Qb + (size_t)B_ * T_ * 64;
    ushort_t* Vb = Kb + (size_t)B_ * T_ * 64;

    float* gout = (float*)d_out;

    dim3 g1(B_ * (T_ / 64), 2);
    proj_kernel<<<g1, 256, 0, stream>>>(y1, y2, Wq, Wk, Wv, Qb, Kb, Vb);

    attn_kernel<<<dim3(B_ * (T_ / 16)), 256, 0, stream>>>(
        (const uint*)Qb, (const uint*)Kb, (const uint*)Vb, gout);
}